// Round 9
// baseline (119.414 us; speedup 1.0000x reference)
//
#include <hip/hip_runtime.h>
#include <stdint.h>

// XGBoost forest inference: B=50000, F=256, T=1000, depth=6, 127 nodes/tree.
// v9 = v8 (barrier-free per-wave staged all-LDS walk, validated 83cy/visit)
// plus two modeled fixes:
//  1. leaf software pipeline: consume tile t-1's leaf values AFTER tile t's
//     walk (loads issued a full tile earlier -> L2 latency fully hidden);
//     the per-tile fence `s_waitcnt vmcnt(4)` then only has the 4 just-
//     issued stage ops in its newer-set (dummy re-stage in the last two
//     tiles keeps the count compile-time constant).
//  2. no dummy-tree walk: trees 1000-1023 live in tile 15 at wave slots
//     wid>=5; those waves skip tile 15's walk+leaf (LDS is the CU-shared
//     bottleneck pipe -> skipped issue cycles are real savings).
// Lessons kept: no divergent VMEM in the walk chain (v2/v4/v5), no scalar
// loads in the walk (v3), no register-cached tops (v6), leaf off-chain via
// global (v7), per-wave DMA staging with counted vmcnt fences (v8).

#define NFEAT   256
#define NNODES  127
#define NTREES  1000
#define TPAD    1024
#define SPB     64       // samples per block (= lanes per wave)
#define NTH     512      // 8 waves
#define TILE_T  64       // trees per tile; 8 per wave
#define TPW     8        // trees per wave per tile
#define MID_DW  128      // dwords per tree record: node n (0..62) int2 at dw 2n
#define NTILES  16       // 16 tiles cover 1024 padded trees (tile 15 partial)
#define FULLB   768      // full blocks (sample tiles 0..767): 3 clean rounds
#define LEFT    14       // leftover sample tiles 768..781, tree-sliced
#define SLICES  16

#define MID_OFF  0                       // int [TPAD][128] = 512 KB
#define LEAF_OFF (TPAD * 512)            // float[TPAD][64] = 256 KB
#define WS_NEED  (TPAD * 512 + TPAD * 256)

typedef __attribute__((address_space(1))) const unsigned char ga_u8;
typedef __attribute__((address_space(3))) unsigned char       la_u8;

// pack into d_ws; trees >= NTREES are zero dummies (staged but never walked).
// Also initializes out[] for the tail samples (tail blocks atomicAdd).
__global__ void xgb_pack_kernel(const int* __restrict__ idx,
                                const float* __restrict__ cond,
                                char* __restrict__ ws,
                                const float* __restrict__ base_score,
                                float* __restrict__ out, int B)
{
    const int i = blockIdx.x * 256 + threadIdx.x;
    if (i < B - FULLB * SPB) out[FULLB * SPB + i] = base_score[0];
    if (i >= TPAD * NNODES) return;
    const int t  = i / NNODES;
    const int nd = i - t * NNODES;
    int   f = 0;
    float c = 0.0f;
    if (t < NTREES) { f = idx[i]; c = cond[i]; }
    if (nd < 63) {
        int* mid = (int*)(ws + MID_OFF) + (size_t)t * MID_DW;
        mid[2 * nd]     = f;
        mid[2 * nd + 1] = __float_as_int(c);
    } else {
        ((float*)(ws + LEAF_OFF))[t * 64 + (nd - 63)] = c;
    }
}

// per-wave stage: this wave's 8 trees of tile tileIdx (4KB = 4 x 1KB chunks)
// into its own LDS buffer. LDS dest = wave-uniform base (+ implicit lane*16);
// global src per-lane. No cross-wave dependency -> no barrier needed.
__device__ __forceinline__ void stage_wave(const char* __restrict__ midG,
                                           int tileIdx, char* dst,
                                           int wid, int lane)
{
    const char* src = midG + ((size_t)tileIdx * TILE_T + wid * TPW) * 512;
#pragma unroll
    for (int c = 0; c < 4; ++c) {
#if __has_builtin(__builtin_amdgcn_global_load_lds)
        __builtin_amdgcn_global_load_lds(
            (ga_u8*)(uintptr_t)(src + c * 1024 + lane * 16),
            (la_u8*)(uintptr_t)(dst + c * 1024), 16, 0, 0);
#else
        *reinterpret_cast<int4*>(dst + c * 1024 + lane * 16) =
            *reinterpret_cast<const int4*>(src + c * 1024 + lane * 16);
#endif
    }
}

__global__ __launch_bounds__(NTH, 1) void xgb_forest_kernel(
    const float* __restrict__ x,
    const char*  __restrict__ ws,
    const float* __restrict__ base_score,
    float* __restrict__ out, int B)
{
    __shared__ float xT[NFEAT * SPB];                         // 64 KB
    __shared__ __align__(16) int midL[8][2][TPW * MID_DW];    // 64 KB
    __shared__ float partials[8 * SPB];                       //  2 KB

    const char*  midG  = ws + MID_OFF;
    const float* leafG = (const float*)(ws + LEAF_OFF);

    const int tid = threadIdx.x;
    const int bid = blockIdx.x;
    const int s   = tid & 63;
    const int wid = tid >> 6;

    // block role: full (16 tree-tiles) or one tree-slice of a leftover tile
    int sTile, tTile0, nTiles;
    if (bid < FULLB) {
        sTile = bid;              tTile0 = 0;        nTiles = NTILES;
    } else {
        const int u = bid - FULLB;                   // 0..223
        sTile = FULLB + (u >> 4); tTile0 = u & 15;   nTiles = 1;
    }
    const int sbase = sTile * SPB;

    // prologue: stage first (two) tiles for THIS wave; flies under x-staging
    stage_wave(midG, tTile0, (char*)midL[wid][0], wid, s);
    if (nTiles > 1) stage_wave(midG, tTile0 + 1, (char*)midL[wid][1], wid, s);

    // ---- stage x tile, transposed (gather bank = sample%32, conflict-free)
    {
        const int sq = tid & 15;
        const int cg = tid >> 4;               // 0..31
        for (int rg = 0; rg < 4; ++rg) {
            const int  sl = rg * 16 + sq;
            const bool ok = (sbase + sl) < B;
            for (int ci = 0; ci < 2; ++ci) {
                const int c4 = ci * 32 + cg;
                float4 v = make_float4(0.f, 0.f, 0.f, 0.f);
                if (ok)
                    v = *reinterpret_cast<const float4*>(
                        &x[(size_t)(sbase + sl) * NFEAT + c4 * 4]);
                xT[(c4 * 4 + 0) * SPB + sl] = v.x;
                xT[(c4 * 4 + 1) * SPB + sl] = v.y;
                xT[(c4 * 4 + 2) * SPB + sl] = v.z;
                xT[(c4 * 4 + 3) * SPB + sl] = v.w;
            }
        }
    }
    __syncthreads();   // xT visible to all waves; vmcnt drained (tiles 0,1 in)

    const float* xs = &xT[s];
    float acc = 0.0f;
    float lv[TPW];
#pragma unroll
    for (int j = 0; j < TPW; ++j) lv[j] = 0.0f;

    for (int t = 0; t < nTiles; ++t) {
        const int  tileIdx = tTile0 + t;
        const int* mbuf    = &midL[wid][t & 1][0];
        // tile 15 wave slots wid>=5 hold only dummy trees (1000..1023): skip
        const bool active  = (tileIdx < NTILES - 1) || (wid < 5);

        int node[TPW];
#pragma unroll
        for (int j = 0; j < TPW; ++j) node[j] = 0;

        if (active) {
            // levels 0-5: all-LDS (b64 tree + b32 gather, conflict-free/2-way)
#pragma unroll
            for (int d = 0; d < 6; ++d) {
#pragma unroll
                for (int j = 0; j < TPW; ++j) {
                    const int2 nd = *reinterpret_cast<const int2*>(
                        &mbuf[j * MID_DW + 2 * node[j]]);
                    const float xv = xs[nd.x * SPB];
                    node[j] = 2 * node[j] + 1 +
                              (int)((xv - __int_as_float(nd.y)) > 0.0f);
                }
            }
        }

        // consume PREVIOUS tile's leaf values (loads issued one full tile
        // ago -> compiler-inserted vmcnt waits are free; this also drains
        // stage(t+1) which is older, making the walk of t+1 safe)
#pragma unroll
        for (int j = 0; j < TPW; ++j) acc += lv[j];

        // re-stage the buffer just walked with tile t+2 (per-wave DMA);
        // dummy re-stage of the current tile keeps the fence count constant
        const int st = (t + 2 < nTiles) ? t + 2 : t;
        stage_wave(midG, tTile0 + st, (char*)&midL[wid][t & 1][0], wid, s);

        // wave-local pipeline fence: newer-set = the 4 just-issued stage ops;
        // everything older (incl. stage(t+1)) must be complete.
        asm volatile("s_waitcnt vmcnt(4)" ::: "memory");

        // leaf loads for THIS tile (chain-independent; consumed next tile)
        const int tgB = tileIdx * TILE_T + wid * TPW;
        if (active) {
#pragma unroll
            for (int j = 0; j < TPW; ++j)
                lv[j] = leafG[(size_t)(tgB + j) * 64 + (node[j] - 63)];
        } else {
#pragma unroll
            for (int j = 0; j < TPW; ++j) lv[j] = 0.0f;
        }
    }
#pragma unroll
    for (int j = 0; j < TPW; ++j) acc += lv[j];   // final tile's leaves

    partials[wid * SPB + s] = acc;
    __syncthreads();
    if (tid < SPB && sbase + tid < B) {
        float r = 0.0f;
#pragma unroll
        for (int l = 0; l < 8; ++l) r += partials[l * SPB + tid];
        if (bid < FULLB) out[sbase + tid] = r + base_score[0];
        else             atomicAdd(&out[sbase + tid], r);  // ulp noise << 2.7
    }
}

// correctness insurance if ws is ever too small (not expected).
__global__ void xgb_naive_kernel(const float* __restrict__ x,
                                 const int*   __restrict__ split_idx,
                                 const float* __restrict__ split_cond,
                                 const float* __restrict__ base_score,
                                 float* __restrict__ out, int B)
{
    const int sI = blockIdx.x * 256 + threadIdx.x;
    if (sI >= B) return;
    float acc = base_score[0];
    for (int t = 0; t < NTREES; ++t) {
        int node = 0;
        for (int d = 0; d < 6; ++d) {
            const int g = t * NNODES + node;
            const float xv = x[(size_t)sI * NFEAT + split_idx[g]];
            node = 2 * node + 1 + (int)((xv - split_cond[g]) > 0.0f);
        }
        acc += split_cond[t * NNODES + node];
    }
    out[sI] = acc;
}

extern "C" void kernel_launch(void* const* d_in, const int* in_sizes, int n_in,
                              void* d_out, int out_size, void* d_ws, size_t ws_size,
                              hipStream_t stream)
{
    const float* x          = (const float*)d_in[0];
    const int*   split_idx  = (const int*)d_in[1];
    const float* split_cond = (const float*)d_in[2];
    const float* base_score = (const float*)d_in[3];
    float*       out        = (float*)d_out;

    const int B = out_size;                               // 50000

    if (ws_size < (size_t)WS_NEED) {
        xgb_naive_kernel<<<(B + 255) / 256, 256, 0, stream>>>(
            x, split_idx, split_cond, base_score, out, B);
        return;
    }

    xgb_pack_kernel<<<(TPAD * NNODES + 255) / 256, 256, 0, stream>>>(
        split_idx, split_cond, (char*)d_ws, base_score, out, B);

    const int grid = FULLB + LEFT * SLICES;               // 992
    xgb_forest_kernel<<<grid, NTH, 0, stream>>>(
        x, (const char*)d_ws, base_score, out, B);
}

// Round 10
// 116.907 us; speedup vs baseline: 1.0214x; 1.0214x over previous
//
#include <hip/hip_runtime.h>
#include <stdint.h>

// XGBoost forest inference: B=50000, F=256, T=1000, depth=6, 127 nodes/tree.
// v10 = v8 verbatim (validated best: 116.5us). v9's leaf software-pipeline
// was falsified (+3us: leaf latency was already TLP-hidden; the lv-carry,
// predication, and dummy re-stage added pure overhead). This structure is
// at its LDS-issue floor: 782K wave-visits x 83cy / 256 CU ~= 106us walk +
// x-stage + pack + tail quantization ~= 117us measured.
// Design: barrier-free per-wave-staged all-LDS walk.
//  - walk levels 0-5 all-LDS (b64 tree read + b32 transposed-x gather per
//    level, conflict-free: gather bank = sample%32; tree node n at dw 2n).
//  - leaf from global (chain-independent; latency amortized by TLP).
//  - tree tiles staged PER-WAVE via global_load_lds (per-wave DMA) into
//    per-wave double-buffered LDS; inter-tile dep enforced by counted
//    `s_waitcnt vmcnt(4)` (stage(t+2) in flight, older drained). 2 barriers
//    per block total.
//  - makespan: 768 full blocks (3 clean rounds of 256 CUs) + 14 leftover
//    sample-tiles sliced into 16 tree-slice blocks each (atomicAdd tail).
// Falsified alternatives: divergent VMEM in walk chain (v2/v4/v5), scalar
// loads in walk (v3), register-cached tops (v6), leaf pipelining (v9),
// per-tile block-wide barriers (v7).

#define NFEAT   256
#define NNODES  127
#define NTREES  1000
#define TPAD    1024
#define SPB     64       // samples per block (= lanes per wave)
#define NTH     512      // 8 waves
#define TILE_T  64       // trees per tile; 8 per wave
#define TPW     8        // trees per wave per tile
#define MID_DW  128      // dwords per tree record: node n (0..62) int2 at dw 2n
#define NTILES  16       // full block walks 1024 padded trees
#define FULLB   768      // full-tile blocks (sample tiles 0..767)
#define LEFT    14       // leftover sample tiles 768..781, tree-sliced
#define SLICES  16

#define MID_OFF  0                       // int [TPAD][128] = 512 KB
#define LEAF_OFF (TPAD * 512)            // float[TPAD][64] = 256 KB
#define WS_NEED  (TPAD * 512 + TPAD * 256)

typedef __attribute__((address_space(1))) const unsigned char ga_u8;
typedef __attribute__((address_space(3))) unsigned char       la_u8;

// pack into d_ws; trees >= NTREES are zero dummies (leaf 0 -> contribute 0).
// Also initializes out[] for the 896 tail samples (tail blocks atomicAdd).
__global__ void xgb_pack_kernel(const int* __restrict__ idx,
                                const float* __restrict__ cond,
                                char* __restrict__ ws,
                                const float* __restrict__ base_score,
                                float* __restrict__ out, int B)
{
    const int i = blockIdx.x * 256 + threadIdx.x;
    if (i < B - FULLB * SPB) out[FULLB * SPB + i] = base_score[0];
    if (i >= TPAD * NNODES) return;
    const int t  = i / NNODES;
    const int nd = i - t * NNODES;
    int   f = 0;
    float c = 0.0f;
    if (t < NTREES) { f = idx[i]; c = cond[i]; }
    if (nd < 63) {
        int* mid = (int*)(ws + MID_OFF) + (size_t)t * MID_DW;
        mid[2 * nd]     = f;
        mid[2 * nd + 1] = __float_as_int(c);
    } else {
        ((float*)(ws + LEAF_OFF))[t * 64 + (nd - 63)] = c;
    }
}

// per-wave stage: this wave's 8 trees of tile tileIdx (4KB = 4 x 1KB chunks)
// into its own LDS buffer. LDS dest = wave-uniform base (+ implicit lane*16);
// global src per-lane. No cross-wave dependency -> no barrier needed.
__device__ __forceinline__ void stage_wave(const char* __restrict__ midG,
                                           int tileIdx, char* dst,
                                           int wid, int lane)
{
    const char* src = midG + ((size_t)tileIdx * TILE_T + wid * TPW) * 512;
#pragma unroll
    for (int c = 0; c < 4; ++c) {
#if __has_builtin(__builtin_amdgcn_global_load_lds)
        __builtin_amdgcn_global_load_lds(
            (ga_u8*)(uintptr_t)(src + c * 1024 + lane * 16),
            (la_u8*)(uintptr_t)(dst + c * 1024), 16, 0, 0);
#else
        *reinterpret_cast<int4*>(dst + c * 1024 + lane * 16) =
            *reinterpret_cast<const int4*>(src + c * 1024 + lane * 16);
#endif
    }
}

__global__ __launch_bounds__(NTH, 1) void xgb_forest_kernel(
    const float* __restrict__ x,
    const char*  __restrict__ ws,
    const float* __restrict__ base_score,
    float* __restrict__ out, int B)
{
    __shared__ float xT[NFEAT * SPB];                         // 64 KB
    __shared__ __align__(16) int midL[8][2][TPW * MID_DW];    // 64 KB
    __shared__ float partials[8 * SPB];                       //  2 KB

    const char*  midG  = ws + MID_OFF;
    const float* leafG = (const float*)(ws + LEAF_OFF);

    const int tid = threadIdx.x;
    const int bid = blockIdx.x;
    const int s   = tid & 63;
    const int wid = tid >> 6;

    // block role: full (16 tree-tiles) or one tree-slice of a leftover tile
    int sTile, tTile0, nTiles;
    if (bid < FULLB) {
        sTile = bid;              tTile0 = 0;        nTiles = NTILES;
    } else {
        const int u = bid - FULLB;                   // 0..223
        sTile = FULLB + (u >> 4); tTile0 = u & 15;   nTiles = 1;
    }
    const int sbase = sTile * SPB;

    // prologue: stage first (two) tiles for THIS wave; flies under x-staging
    stage_wave(midG, tTile0, (char*)midL[wid][0], wid, s);
    if (nTiles > 1) stage_wave(midG, tTile0 + 1, (char*)midL[wid][1], wid, s);

    // ---- stage x tile, transposed (gather bank = sample%32, conflict-free)
    {
        const int sq = tid & 15;
        const int cg = tid >> 4;               // 0..31
        for (int rg = 0; rg < 4; ++rg) {
            const int  sl = rg * 16 + sq;
            const bool ok = (sbase + sl) < B;
            for (int ci = 0; ci < 2; ++ci) {
                const int c4 = ci * 32 + cg;
                float4 v = make_float4(0.f, 0.f, 0.f, 0.f);
                if (ok)
                    v = *reinterpret_cast<const float4*>(
                        &x[(size_t)(sbase + sl) * NFEAT + c4 * 4]);
                xT[(c4 * 4 + 0) * SPB + sl] = v.x;
                xT[(c4 * 4 + 1) * SPB + sl] = v.y;
                xT[(c4 * 4 + 2) * SPB + sl] = v.z;
                xT[(c4 * 4 + 3) * SPB + sl] = v.w;
            }
        }
    }
    __syncthreads();   // xT visible to all waves; drains vmcnt (tiles 0,1 landed)

    const float* xs = &xT[s];
    float acc = 0.0f;

    for (int t = 0; t < nTiles; ++t) {
        const int* mbuf = &midL[wid][t & 1][0];
        const int  tgB  = (tTile0 + t) * TILE_T + wid * TPW;  // padded tree base

        int node[TPW];
#pragma unroll
        for (int j = 0; j < TPW; ++j) node[j] = 0;

        // levels 0-5: all-LDS (b64 tree + b32 gather, conflict-free/2-way)
#pragma unroll
        for (int d = 0; d < 6; ++d) {
#pragma unroll
            for (int j = 0; j < TPW; ++j) {
                const int2 nd = *reinterpret_cast<const int2*>(
                    &mbuf[j * MID_DW + 2 * node[j]]);
                const float xv = xs[nd.x * SPB];
                node[j] = 2 * node[j] + 1 +
                          (int)((xv - __int_as_float(nd.y)) > 0.0f);
            }
        }

        // leaf: global, chain-independent (addresses ready; latency amortizes)
#pragma unroll
        for (int j = 0; j < TPW; ++j)
            acc += leafG[(size_t)(tgB + j) * 64 + (node[j] - 63)];

        // re-stage the buffer just walked with tile t+2 (per-wave DMA)
        if (t + 2 < nTiles)
            stage_wave(midG, tTile0 + t + 2, (char*)midL[wid][t & 1], wid, s);

        // wave-local pipeline fence: stage(t+1) (and older) complete; allow
        // the 4 just-issued stage(t+2) ops to remain in flight.
        asm volatile("s_waitcnt vmcnt(4)" ::: "memory");
    }

    partials[wid * SPB + s] = acc;
    __syncthreads();
    if (tid < SPB && sbase + tid < B) {
        float r = 0.0f;
#pragma unroll
        for (int l = 0; l < 8; ++l) r += partials[l * SPB + tid];
        if (bid < FULLB) out[sbase + tid] = r + base_score[0];
        else             atomicAdd(&out[sbase + tid], r);  // ulp noise << 2.7
    }
}

// correctness insurance if ws is ever too small (not expected).
__global__ void xgb_naive_kernel(const float* __restrict__ x,
                                 const int*   __restrict__ split_idx,
                                 const float* __restrict__ split_cond,
                                 const float* __restrict__ base_score,
                                 float* __restrict__ out, int B)
{
    const int sI = blockIdx.x * 256 + threadIdx.x;
    if (sI >= B) return;
    float acc = base_score[0];
    for (int t = 0; t < NTREES; ++t) {
        int node = 0;
        for (int d = 0; d < 6; ++d) {
            const int g = t * NNODES + node;
            const float xv = x[(size_t)sI * NFEAT + split_idx[g]];
            node = 2 * node + 1 + (int)((xv - split_cond[g]) > 0.0f);
        }
        acc += split_cond[t * NNODES + node];
    }
    out[sI] = acc;
}

extern "C" void kernel_launch(void* const* d_in, const int* in_sizes, int n_in,
                              void* d_out, int out_size, void* d_ws, size_t ws_size,
                              hipStream_t stream)
{
    const float* x          = (const float*)d_in[0];
    const int*   split_idx  = (const int*)d_in[1];
    const float* split_cond = (const float*)d_in[2];
    const float* base_score = (const float*)d_in[3];
    float*       out        = (float*)d_out;

    const int B = out_size;                               // 50000

    if (ws_size < (size_t)WS_NEED) {
        xgb_naive_kernel<<<(B + 255) / 256, 256, 0, stream>>>(
            x, split_idx, split_cond, base_score, out, B);
        return;
    }

    xgb_pack_kernel<<<(TPAD * NNODES + 255) / 256, 256, 0, stream>>>(
        split_idx, split_cond, (char*)d_ws, base_score, out, B);

    const int grid = FULLB + LEFT * SLICES;               // 992
    xgb_forest_kernel<<<grid, NTH, 0, stream>>>(
        x, (const char*)d_ws, base_score, out, B);
}